// Round 1
// 907.442 us; speedup vs baseline: 1.0061x; 1.0061x over previous
//
#include <hip/hip_runtime.h>
#include <hip/hip_bf16.h>

#define BB 4
#define MM 50000
#define FINF 128
#define FOUTF 128
#define KCH 4
#define EE 800000
#define NROWS (BB*MM)      // 200000
#define XC 512             // columns of X = B*FIN
#define CD 512             // reduction dim = FIN*K

__device__ __forceinline__ float bf2f(unsigned short u){
    union{unsigned int i; float f;} v; v.i = ((unsigned int)u) << 16; return v.f;
}
__device__ __forceinline__ unsigned short f2bf(float f){
    union{float f; unsigned int i;} v; v.f = f;
    unsigned int r = v.i + 0x7FFF + ((v.i >> 16) & 1);   // RNE
    return (unsigned short)(r >> 16);
}

typedef __bf16 bf16x8 __attribute__((ext_vector_type(8)));
typedef float  f32x4  __attribute__((ext_vector_type(4)));

// ---- X0[m][b*128+f] = bf16(x[b][m][f]) ----
__global__ __launch_bounds__(256) void k_init_x0(const float* __restrict__ x,
                                                 unsigned short* __restrict__ X0){
    int tid = blockIdx.x*256 + threadIdx.x;          // one float4 each
    if (tid >= BB*MM*FINF/4) return;
    int f4 = tid & 31;
    int t  = tid >> 5;                               // b*MM + m
    int m  = t % MM, b = t / MM;
    float4 v = ((const float4*)x)[tid];
    ushort4 o;
    o.x = f2bf(v.x); o.y = f2bf(v.y); o.z = f2bf(v.z); o.w = f2bf(v.w);
    *(ushort4*)(X0 + (size_t)m*XC + b*FINF + f4*4) = o;
}

// ---- Wt swizzled into MFMA B-fragment order ----
// gemm wants: lane (g=lane>>4, l16=lane&15), frag (ns, ks), elem j ->
//   B[n = ns*16+l16][c = ks*32+g*8+j], stored at ((ns*16+ks)*64 + lane)*8 + j
// value meaning: c = kc*128 + f  ->  kernel[(f*K+kc)*FOUT + n]
__global__ __launch_bounds__(256) void k_prepw(const float* __restrict__ kern,
                                               unsigned short* __restrict__ Wt){
    int tid = blockIdx.x*256 + threadIdx.x;          // 65536
    int c = tid & 511, n = tid >> 9;
    int kc = c >> 7, f = c & 127;
    int ns = n >> 4, l16 = n & 15;
    int ks = c >> 5, rem = c & 31, g = rem >> 3, j = rem & 7;
    int lane = g*16 + l16;
    Wt[((ns*16 + ks)*64 + lane)*8 + j] = f2bf(kern[(f*KCH + kc)*FOUTF + n]);
}

// ---- CSR build ----
__global__ __launch_bounds__(256) void k_hist(const int* __restrict__ rows, int* __restrict__ counts){
    int e = blockIdx.x*256 + threadIdx.x;
    if (e < EE) atomicAdd(&counts[rows[e]], 1);
}

__global__ __launch_bounds__(1024) void k_scan(const int* __restrict__ counts,
                                               int* __restrict__ offs, int* __restrict__ cursor){
    __shared__ int part[1024];
    const int CH = (MM + 1023) / 1024;               // 49
    int t = threadIdx.x;
    int lo = t*CH; if (lo > MM) lo = MM;
    int hi = lo + CH; if (hi > MM) hi = MM;
    int s = 0;
    for (int i = lo; i < hi; ++i) s += counts[i];
    part[t] = s; __syncthreads();
    for (int d = 1; d < 1024; d <<= 1){
        int v = (t >= d) ? part[t-d] : 0;
        __syncthreads();
        part[t] += v;
        __syncthreads();
    }
    int run = (t == 0) ? 0 : part[t-1];
    for (int i = lo; i < hi; ++i){
        offs[i] = run; cursor[i] = run; run += counts[i];
    }
    if (t == 1023) offs[MM] = part[1023];
}

__global__ __launch_bounds__(256) void k_scatter(const int* __restrict__ rows, const int* __restrict__ cols,
                                                 const float* __restrict__ vals, int* __restrict__ cursor,
                                                 int* __restrict__ colv, float* __restrict__ valv){
    int e = blockIdx.x*256 + threadIdx.x;
    if (e >= EE) return;
    int r = rows[e];
    int pos = atomicAdd(&cursor[r], 1);
    colv[pos] = cols[e]; valv[pos] = vals[e];
}

// ---- Xout = alpha * (L @ Xin) - (sub ? Xprev : 0), one block per row ----
// Latency-bound fix: 4x edge unroll (4 independent gathers in flight per wave)
// + col/val prefetched one burst ahead so the gather chain never waits on colv.
// Accumulation order per component is identical to the serial loop (bitwise-same numerics).
__global__ __launch_bounds__(128) void k_spmm(const unsigned short* __restrict__ Xin,
                                              const unsigned short* __restrict__ Xprev,
                                              unsigned short* __restrict__ Xout,
                                              const int* __restrict__ offs,
                                              const int* __restrict__ colv,
                                              const float* __restrict__ valv,
                                              float alpha, int sub){
    int m = blockIdx.x, t = threadIdx.x;
    int c0 = t*4;
    int start = offs[m], end = offs[m+1];
    float a0=0.f, a1=0.f, a2=0.f, a3=0.f;

    int n  = end - start;
    int nb = n & ~3;                                 // burst-of-4 region
    int burst_end = start + nb;
    int j = start;

    int   cc[4];
    float vv[4];
    if (j < burst_end){
        #pragma unroll
        for (int q = 0; q < 4; ++q){ cc[q] = colv[j+q]; vv[q] = valv[j+q]; }
    }
    while (j < burst_end){
        int   c_[4];
        float v_[4];
        #pragma unroll
        for (int q = 0; q < 4; ++q){ c_[q] = cc[q]; v_[q] = vv[q]; }
        j += 4;
        if (j < burst_end){                          // prefetch next burst's col/val
            #pragma unroll
            for (int q = 0; q < 4; ++q){ cc[q] = colv[j+q]; vv[q] = valv[j+q]; }
        }
        ushort4 xv[4];
        #pragma unroll
        for (int q = 0; q < 4; ++q)                  // 4 independent 512B/wave gathers in flight
            xv[q] = *(const ushort4*)(Xin + (size_t)c_[q]*XC + c0);
        #pragma unroll
        for (int q = 0; q < 4; ++q){
            a0 += v_[q]*bf2f(xv[q].x); a1 += v_[q]*bf2f(xv[q].y);
            a2 += v_[q]*bf2f(xv[q].z); a3 += v_[q]*bf2f(xv[q].w);
        }
    }
    for (; j < end; ++j){                            // remainder (0..3 edges)
        int col = colv[j]; float val = valv[j];
        ushort4 xv = *(const ushort4*)(Xin + (size_t)col*XC + c0);
        a0 += val*bf2f(xv.x); a1 += val*bf2f(xv.y);
        a2 += val*bf2f(xv.z); a3 += val*bf2f(xv.w);
    }

    a0 *= alpha; a1 *= alpha; a2 *= alpha; a3 *= alpha;
    if (sub){
        ushort4 pv = *(const ushort4*)(Xprev + (size_t)m*XC + c0);
        a0 -= bf2f(pv.x); a1 -= bf2f(pv.y); a2 -= bf2f(pv.z); a3 -= bf2f(pv.w);
    }
    ushort4 o; o.x = f2bf(a0); o.y = f2bf(a1); o.z = f2bf(a2); o.w = f2bf(a3);
    *(ushort4*)(Xout + (size_t)m*XC + c0) = o;
}

// ---- GEMM: wave tile 64 rows x 128 cols, B fragments coalesced, 2-stage pipeline ----
__global__ __launch_bounds__(256, 2) void k_gemm(const unsigned short* __restrict__ X0,
                                                 const unsigned short* __restrict__ X1,
                                                 const unsigned short* __restrict__ X2,
                                                 const unsigned short* __restrict__ X3,
                                                 const unsigned short* __restrict__ Wt,
                                                 float* __restrict__ Y){
    const int wave = threadIdx.x >> 6;
    const int lane = threadIdx.x & 63;
    const int l16  = lane & 15;
    const int g    = lane >> 4;                       // 0..3
    const int r0   = blockIdx.x*256 + wave*64;

    int aoff[4];                                      // short-index offsets into X
    #pragma unroll
    for (int i = 0; i < 4; ++i){
        int ra = r0 + i*16 + l16;
        if (ra >= NROWS) ra = NROWS-1;
        aoff[i] = (ra % MM)*XC + (ra / MM)*FINF + g*8;
    }

    const unsigned short* const Xs[4] = {X0, X1, X2, X3};

    f32x4 acc[4][8];
    #pragma unroll
    for (int i = 0; i < 4; ++i)
        #pragma unroll
        for (int j = 0; j < 8; ++j) acc[i][j] = (f32x4){0.f,0.f,0.f,0.f};

    bf16x8 a_cur[4], b_cur[8], a_nxt[4], b_nxt[8];

    {   // preload ks = 0
        const unsigned short* Xb = Xs[0];
        #pragma unroll
        for (int i = 0; i < 4; ++i) a_cur[i] = *(const bf16x8*)(Xb + aoff[i]);
        #pragma unroll
        for (int ns = 0; ns < 8; ++ns) b_cur[ns] = *(const bf16x8*)(Wt + (ns*16)*512 + lane*8);
    }

    #pragma unroll
    for (int ks = 0; ks < 16; ++ks){
        if (ks < 15){
            const int kn = ks + 1;
            const unsigned short* Xb = Xs[kn >> 2];
            const int f0 = (kn & 3)*32;
            #pragma unroll
            for (int i = 0; i < 4; ++i) a_nxt[i] = *(const bf16x8*)(Xb + aoff[i] + f0);
            #pragma unroll
            for (int ns = 0; ns < 8; ++ns) b_nxt[ns] = *(const bf16x8*)(Wt + (ns*16 + kn)*512 + lane*8);
        }
        #pragma unroll
        for (int ns = 0; ns < 8; ++ns)
            #pragma unroll
            for (int i = 0; i < 4; ++i)
                acc[i][ns] = __builtin_amdgcn_mfma_f32_16x16x32_bf16(a_cur[i], b_cur[ns], acc[i][ns], 0, 0, 0);
        #pragma unroll
        for (int i = 0; i < 4; ++i) a_cur[i] = a_nxt[i];
        #pragma unroll
        for (int ns = 0; ns < 8; ++ns) b_cur[ns] = b_nxt[ns];
    }

    #pragma unroll
    for (int i = 0; i < 4; ++i){
        #pragma unroll
        for (int reg = 0; reg < 4; ++reg){
            int r = r0 + i*16 + g*4 + reg;
            if (r < NROWS){
                #pragma unroll
                for (int ns = 0; ns < 8; ++ns){
                    float v = acc[i][ns][reg];
                    Y[(size_t)r*FOUTF + ns*16 + l16] = v > 0.f ? v : 0.f;
                }
            }
        }
    }
}

// ---- column sums of Y per batch: grid (256 chunks, B), 256 thr ----
__global__ __launch_bounds__(256) void k_colmean(const float* __restrict__ Y, float* __restrict__ sacc){
    int b = blockIdx.y, t = threadIdx.x;
    int c4 = t & 31, rs = t >> 5;
    const int rows = (MM + gridDim.x - 1) / gridDim.x;
    int m0 = blockIdx.x * rows;
    int mend = m0 + rows; if (mend > MM) mend = MM;
    float4 s = {0.f,0.f,0.f,0.f};
    for (int m = m0 + rs; m < mend; m += 8){
        float4 v = *(const float4*)(Y + ((size_t)b*MM + m)*FOUTF + c4*4);
        s.x += v.x; s.y += v.y; s.z += v.z; s.w += v.w;
    }
    __shared__ float4 red[8][32];
    red[rs][c4] = s;
    __syncthreads();
    if (t < 32){
        float4 a = red[0][t];
        #pragma unroll
        for (int i = 1; i < 8; ++i){
            float4 v = red[i][t];
            a.x += v.x; a.y += v.y; a.z += v.z; a.w += v.w;
        }
        atomicAdd(&sacc[b*FOUTF + t*4 + 0], a.x);
        atomicAdd(&sacc[b*FOUTF + t*4 + 1], a.y);
        atomicAdd(&sacc[b*FOUTF + t*4 + 2], a.z);
        atomicAdd(&sacc[b*FOUTF + t*4 + 3], a.w);
    }
}

// ---- SE MLP: u = sigmoid(swish(mean @ Wd + bd) @ Wu + bu) ----
__global__ __launch_bounds__(128) void k_se(const float* __restrict__ sacc,
                                            const float* __restrict__ Wd, const float* __restrict__ bd,
                                            const float* __restrict__ Wu, const float* __restrict__ bu,
                                            float* __restrict__ u){
    int b = blockIdx.x, t = threadIdx.x;
    __shared__ float sm[128];
    __shared__ float dsh[16];
    sm[t] = sacc[b*FOUTF + t] * (1.0f/MM);
    __syncthreads();
    if (t < 16){
        float a = bd[t];
        for (int f = 0; f < 128; ++f) a += sm[f]*Wd[f*16 + t];
        dsh[t] = a / (1.f + expf(-a));                // swish
    }
    __syncthreads();
    float a = bu[t];
    for (int j = 0; j < 16; ++j) a += dsh[j]*Wu[j*FOUTF + t];
    u[b*FOUTF + t] = 1.f/(1.f + expf(-a));
}

// ---- out = Y * u[b] ----
__global__ __launch_bounds__(256) void k_scale(const float* __restrict__ Y, const float* __restrict__ u,
                                               float* __restrict__ out){
    int tid = blockIdx.x*256 + threadIdx.x;
    if (tid >= NROWS*FOUTF/4) return;
    int b  = tid / (MM*FOUTF/4);
    int f4 = tid & 31;
    float4 yv = ((const float4*)Y)[tid];
    float4 uv = *(const float4*)(u + b*FOUTF + f4*4);
    float4 o;
    o.x = yv.x*uv.x; o.y = yv.y*uv.y; o.z = yv.z*uv.z; o.w = yv.w*uv.w;
    ((float4*)out)[tid] = o;
}

extern "C" void kernel_launch(void* const* d_in, const int* in_sizes, int n_in,
                              void* d_out, int out_size, void* d_ws, size_t ws_size,
                              hipStream_t stream){
    (void)in_sizes; (void)n_in; (void)out_size; (void)ws_size;
    const float* x    = (const float*)d_in[0];
    const float* lv   = (const float*)d_in[1];
    const int*   lr   = (const int*)d_in[2];
    const int*   lc   = (const int*)d_in[3];
    const float* kern = (const float*)d_in[4];
    const float* Wd   = (const float*)d_in[5];
    const float* bd   = (const float*)d_in[6];
    const float* Wu   = (const float*)d_in[7];
    const float* bu   = (const float*)d_in[8];
    float* out = (float*)d_out;

    char* w = (char*)d_ws;
    size_t off = 0;
    auto take = [&](size_t bytes)->char*{
        char* p = w + off; off += (bytes + 255) & ~(size_t)255; return p;
    };
    unsigned short* X[4];
    for (int i = 0; i < 4; ++i) X[i] = (unsigned short*)take((size_t)MM*XC*2);
    float* Y           = (float*)take((size_t)NROWS*FOUTF*4);
    unsigned short* Wt = (unsigned short*)take((size_t)FOUTF*CD*2);
    int* counts        = (int*)take((size_t)MM*4);
    int* offs          = (int*)take((size_t)(MM+1)*4);
    int* cursor        = (int*)take((size_t)MM*4);
    int* colv          = (int*)take((size_t)EE*4);
    float* valv        = (float*)take((size_t)EE*4);
    float* sacc        = (float*)take((size_t)BB*FOUTF*4);
    float* u           = (float*)take((size_t)BB*FOUTF*4);

    hipMemsetAsync(counts, 0, MM*4, stream);
    hipMemsetAsync(sacc, 0, BB*FOUTF*4, stream);

    k_init_x0<<<25000, 256, 0, stream>>>(x, X[0]);
    k_prepw<<<256, 256, 0, stream>>>(kern, Wt);
    k_hist<<<(EE+255)/256, 256, 0, stream>>>(lr, counts);
    k_scan<<<1, 1024, 0, stream>>>(counts, offs, cursor);
    k_scatter<<<(EE+255)/256, 256, 0, stream>>>(lr, lc, lv, cursor, colv, valv);

    k_spmm<<<MM, 128, 0, stream>>>(X[0], X[0], X[1], offs, colv, valv, 1.0f, 0);
    k_spmm<<<MM, 128, 0, stream>>>(X[1], X[0], X[2], offs, colv, valv, 2.0f, 1);
    k_spmm<<<MM, 128, 0, stream>>>(X[2], X[1], X[3], offs, colv, valv, 2.0f, 1);

    k_gemm<<<(NROWS+255)/256, 256, 0, stream>>>(X[0], X[1], X[2], X[3], Wt, Y);

    dim3 gmean(256, BB);
    k_colmean<<<gmean, 256, 0, stream>>>(Y, sacc);
    k_se<<<BB, 128, 0, stream>>>(sacc, Wd, bd, Wu, bu, u);
    k_scale<<<25000, 256, 0, stream>>>(Y, u, out);
}

// Round 2
// 857.594 us; speedup vs baseline: 1.0646x; 1.0581x over previous
//
#include <hip/hip_runtime.h>
#include <hip/hip_bf16.h>

#define BB 4
#define MM 50000
#define FINF 128
#define FOUTF 128
#define KCH 4
#define EE 800000
#define NROWS (BB*MM)      // 200000
#define XC 512             // columns of X = B*FIN
#define CD 512             // reduction dim = FIN*K
#define SLABS 4
#define SC (XC/SLABS)      // 128 shorts = 256 B per row-slab
#define SCB 512            // counts per scan block
#define NSB ((MM + SCB - 1)/SCB)   // 98

__device__ __forceinline__ float bf2f(unsigned short u){
    union{unsigned int i; float f;} v; v.i = ((unsigned int)u) << 16; return v.f;
}
__device__ __forceinline__ unsigned short f2bf(float f){
    union{float f; unsigned int i;} v; v.f = f;
    unsigned int r = v.i + 0x7FFF + ((v.i >> 16) & 1);   // RNE
    return (unsigned short)(r >> 16);
}

typedef __bf16 bf16x8 __attribute__((ext_vector_type(8)));
typedef float  f32x4  __attribute__((ext_vector_type(4)));

// ---- X0[m][b*128+f] = bf16(x[b][m][f]) ----
__global__ __launch_bounds__(256) void k_init_x0(const float* __restrict__ x,
                                                 unsigned short* __restrict__ X0){
    int tid = blockIdx.x*256 + threadIdx.x;          // one float4 each
    if (tid >= BB*MM*FINF/4) return;
    int f4 = tid & 31;
    int t  = tid >> 5;                               // b*MM + m
    int m  = t % MM, b = t / MM;
    float4 v = ((const float4*)x)[tid];
    ushort4 o;
    o.x = f2bf(v.x); o.y = f2bf(v.y); o.z = f2bf(v.z); o.w = f2bf(v.w);
    *(ushort4*)(X0 + (size_t)m*XC + b*FINF + f4*4) = o;
}

// ---- Wt swizzled into MFMA B-fragment order ----
__global__ __launch_bounds__(256) void k_prepw(const float* __restrict__ kern,
                                               unsigned short* __restrict__ Wt){
    int tid = blockIdx.x*256 + threadIdx.x;          // 65536
    int c = tid & 511, n = tid >> 9;
    int kc = c >> 7, f = c & 127;
    int ns = n >> 4, l16 = n & 15;
    int ks = c >> 5, rem = c & 31, g = rem >> 3, j = rem & 7;
    int lane = g*16 + l16;
    Wt[((ns*16 + ks)*64 + lane)*8 + j] = f2bf(kern[(f*KCH + kc)*FOUTF + n]);
}

// ---- CSR build ----
__global__ __launch_bounds__(256) void k_hist(const int* __restrict__ rows, int* __restrict__ counts){
    int e = blockIdx.x*256 + threadIdx.x;
    if (e < EE) atomicAdd(&counts[rows[e]], 1);
}

// parallel scan, 3 stages (replaces 1-CU serial scan)
__global__ __launch_bounds__(256) void k_scanA(const int* __restrict__ counts, int* __restrict__ part){
    __shared__ int red[256];
    int b = blockIdx.x, t = threadIdx.x;
    int i = b*SCB + t;
    int s = 0;
    if (i < MM) s += counts[i];
    if (i + 256 < (b+1)*SCB && i + 256 < MM) s += counts[i+256];
    red[t] = s; __syncthreads();
    for (int d = 128; d > 0; d >>= 1){
        if (t < d) red[t] += red[t+d];
        __syncthreads();
    }
    if (t == 0) part[b] = red[0];
}

__global__ __launch_bounds__(128) void k_scanB(int* __restrict__ part){
    __shared__ int sh[128];
    int t = threadIdx.x;
    sh[t] = (t < NSB) ? part[t] : 0;
    __syncthreads();
    for (int d = 1; d < 128; d <<= 1){
        int v = (t >= d) ? sh[t-d] : 0;
        __syncthreads();
        sh[t] += v;
        __syncthreads();
    }
    if (t < NSB) part[t] = sh[t];                    // inclusive sums
}

__global__ __launch_bounds__(256) void k_scanC(const int* __restrict__ counts, const int* __restrict__ part,
                                               int* __restrict__ offs, int* __restrict__ cursor){
    __shared__ int sh[256];
    int b = blockIdx.x, t = threadIdx.x;
    int base = (b == 0) ? 0 : part[b-1];
    int i0 = b*SCB + 2*t;
    int c0 = (i0     < MM) ? counts[i0]   : 0;
    int c1 = (i0 + 1 < MM) ? counts[i0+1] : 0;
    sh[t] = c0 + c1; __syncthreads();
    for (int d = 1; d < 256; d <<= 1){
        int v = (t >= d) ? sh[t-d] : 0;
        __syncthreads();
        sh[t] += v;
        __syncthreads();
    }
    int excl = base + sh[t] - (c0 + c1);
    if (i0 < MM){ offs[i0] = excl;      cursor[i0] = excl; }
    if (i0 + 1 < MM){ offs[i0+1] = excl + c0; cursor[i0+1] = excl + c0; }
    if (b == gridDim.x-1 && t == 255) offs[MM] = EE;
}

__global__ __launch_bounds__(256) void k_scatter(const int* __restrict__ rows, const int* __restrict__ cols,
                                                 const float* __restrict__ vals, int* __restrict__ cursor,
                                                 int2* __restrict__ edges){
    int e = blockIdx.x*256 + threadIdx.x;
    if (e >= EE) return;
    int r = rows[e];
    int pos = atomicAdd(&cursor[r], 1);
    edges[pos] = make_int2(cols[e], __float_as_int(vals[e]));
}

// ---- Xout_slab = alpha * (L @ Xin_slab) - (sub ? Xprev_slab : 0) ----
// Column-slab version: per dispatch the gather working set is MM*SC*2 = 12.8 MB
// (fits aggregate L2 / trivially L3), so edge re-reads become cache hits.
// One wave per row; lane covers 2 columns (ushort2). Numerics identical to the
// full-width version (same per-element accumulation order over CSR edges).
__global__ __launch_bounds__(256) void k_spmm_slab(const unsigned short* __restrict__ Xin,
                                                   const unsigned short* __restrict__ Xprev,
                                                   unsigned short* __restrict__ Xout,
                                                   const int* __restrict__ offs,
                                                   const int2* __restrict__ edges,
                                                   float alpha, int sub, int cbase){
    int m    = blockIdx.x*4 + (threadIdx.x >> 6);    // grid 12500 * 4 rows = 50000 exact
    int lane = threadIdx.x & 63;
    size_t c0 = (size_t)cbase + lane*2;
    int start = offs[m], end = offs[m+1];
    float a0 = 0.f, a1 = 0.f;

    int nb = (end - start) & ~3;
    int burst_end = start + nb;
    int j = start;

    int2 ee[4];
    if (j < burst_end){
        #pragma unroll
        for (int q = 0; q < 4; ++q) ee[q] = edges[j+q];
    }
    while (j < burst_end){
        int2 e_[4];
        #pragma unroll
        for (int q = 0; q < 4; ++q) e_[q] = ee[q];
        j += 4;
        if (j < burst_end){
            #pragma unroll
            for (int q = 0; q < 4; ++q) ee[q] = edges[j+q];
        }
        ushort2 xv[4];
        #pragma unroll
        for (int q = 0; q < 4; ++q)
            xv[q] = *(const ushort2*)(Xin + (size_t)e_[q].x*XC + c0);
        #pragma unroll
        for (int q = 0; q < 4; ++q){
            float val = __int_as_float(e_[q].y);
            a0 += val*bf2f(xv[q].x); a1 += val*bf2f(xv[q].y);
        }
    }
    for (; j < end; ++j){
        int2 e = edges[j];
        float val = __int_as_float(e.y);
        ushort2 xv = *(const ushort2*)(Xin + (size_t)e.x*XC + c0);
        a0 += val*bf2f(xv.x); a1 += val*bf2f(xv.y);
    }

    a0 *= alpha; a1 *= alpha;
    if (sub){
        ushort2 pv = *(const ushort2*)(Xprev + (size_t)m*XC + c0);
        a0 -= bf2f(pv.x); a1 -= bf2f(pv.y);
    }
    ushort2 o; o.x = f2bf(a0); o.y = f2bf(a1);
    *(ushort2*)(Xout + (size_t)m*XC + c0) = o;
}

// ---- GEMM: wave tile 64 rows x 128 cols + fused column-sum (replaces k_colmean) ----
__global__ __launch_bounds__(256, 2) void k_gemm(const unsigned short* __restrict__ X0,
                                                 const unsigned short* __restrict__ X1,
                                                 const unsigned short* __restrict__ X2,
                                                 const unsigned short* __restrict__ X3,
                                                 const unsigned short* __restrict__ Wt,
                                                 float* __restrict__ Y,
                                                 float* __restrict__ sacc){
    const int wave = threadIdx.x >> 6;
    const int lane = threadIdx.x & 63;
    const int l16  = lane & 15;
    const int g    = lane >> 4;                       // 0..3
    const int r0   = blockIdx.x*256 + wave*64;

    int aoff[4];                                      // short-index offsets into X
    #pragma unroll
    for (int i = 0; i < 4; ++i){
        int ra = r0 + i*16 + l16;
        if (ra >= NROWS) ra = NROWS-1;
        aoff[i] = (ra % MM)*XC + (ra / MM)*FINF + g*8;
    }

    const unsigned short* const Xs[4] = {X0, X1, X2, X3};

    f32x4 acc[4][8];
    #pragma unroll
    for (int i = 0; i < 4; ++i)
        #pragma unroll
        for (int j = 0; j < 8; ++j) acc[i][j] = (f32x4){0.f,0.f,0.f,0.f};

    bf16x8 a_cur[4], b_cur[8], a_nxt[4], b_nxt[8];

    {   // preload ks = 0
        const unsigned short* Xb = Xs[0];
        #pragma unroll
        for (int i = 0; i < 4; ++i) a_cur[i] = *(const bf16x8*)(Xb + aoff[i]);
        #pragma unroll
        for (int ns = 0; ns < 8; ++ns) b_cur[ns] = *(const bf16x8*)(Wt + (ns*16)*512 + lane*8);
    }

    #pragma unroll
    for (int ks = 0; ks < 16; ++ks){
        if (ks < 15){
            const int kn = ks + 1;
            const unsigned short* Xb = Xs[kn >> 2];
            const int f0 = (kn & 3)*32;
            #pragma unroll
            for (int i = 0; i < 4; ++i) a_nxt[i] = *(const bf16x8*)(Xb + aoff[i] + f0);
            #pragma unroll
            for (int ns = 0; ns < 8; ++ns) b_nxt[ns] = *(const bf16x8*)(Wt + (ns*16 + kn)*512 + lane*8);
        }
        #pragma unroll
        for (int ns = 0; ns < 8; ++ns)
            #pragma unroll
            for (int i = 0; i < 4; ++i)
                acc[i][ns] = __builtin_amdgcn_mfma_f32_16x16x32_bf16(a_cur[i], b_cur[ns], acc[i][ns], 0, 0, 0);
        #pragma unroll
        for (int i = 0; i < 4; ++i) a_cur[i] = a_nxt[i];
        #pragma unroll
        for (int ns = 0; ns < 8; ++ns) b_cur[ns] = b_nxt[ns];
    }

    // epilogue: relu + store + fused per-batch column sums
    __shared__ float ldsum[4][FOUTF];
    const int rblk = blockIdx.x*256;
    const bool fast = ((rblk / MM) == ((rblk + 255) / MM)) && (rblk + 255 < NROWS);
    float csum[8];
    #pragma unroll
    for (int ns = 0; ns < 8; ++ns) csum[ns] = 0.f;

    #pragma unroll
    for (int i = 0; i < 4; ++i){
        #pragma unroll
        for (int reg = 0; reg < 4; ++reg){
            int r = r0 + i*16 + g*4 + reg;
            if (r < NROWS){
                #pragma unroll
                for (int ns = 0; ns < 8; ++ns){
                    float v = acc[i][ns][reg];
                    v = v > 0.f ? v : 0.f;
                    Y[(size_t)r*FOUTF + ns*16 + l16] = v;
                    if (fast) csum[ns] += v;
                    else      atomicAdd(&sacc[(r/MM)*FOUTF + ns*16 + l16], v);
                }
            }
        }
    }
    if (fast){
        const int bidx = rblk / MM;
        #pragma unroll
        for (int ns = 0; ns < 8; ++ns){
            float v = csum[ns];
            v += __shfl_xor(v, 16);                   // sum over g = 0..3 (lanes l16, +16, +32, +48)
            v += __shfl_xor(v, 32);
            csum[ns] = v;
        }
        if (lane < 16){
            #pragma unroll
            for (int ns = 0; ns < 8; ++ns) ldsum[wave][ns*16 + lane] = csum[ns];
        }
        __syncthreads();
        int t = threadIdx.x;
        if (t < FOUTF){
            float s = ldsum[0][t] + ldsum[1][t] + ldsum[2][t] + ldsum[3][t];
            atomicAdd(&sacc[bidx*FOUTF + t], s);
        }
    }
}

// ---- SE MLP: u = sigmoid(swish(mean @ Wd + bd) @ Wu + bu) ----
__global__ __launch_bounds__(128) void k_se(const float* __restrict__ sacc,
                                            const float* __restrict__ Wd, const float* __restrict__ bd,
                                            const float* __restrict__ Wu, const float* __restrict__ bu,
                                            float* __restrict__ u){
    int b = blockIdx.x, t = threadIdx.x;
    __shared__ float sm[128];
    __shared__ float dsh[16];
    sm[t] = sacc[b*FOUTF + t] * (1.0f/MM);
    __syncthreads();
    if (t < 16){
        float a = bd[t];
        for (int f = 0; f < 128; ++f) a += sm[f]*Wd[f*16 + t];
        dsh[t] = a / (1.f + expf(-a));                // swish
    }
    __syncthreads();
    float a = bu[t];
    for (int j = 0; j < 16; ++j) a += dsh[j]*Wu[j*FOUTF + t];
    u[b*FOUTF + t] = 1.f/(1.f + expf(-a));
}

// ---- out = Y * u[b] ----
__global__ __launch_bounds__(256) void k_scale(const float* __restrict__ Y, const float* __restrict__ u,
                                               float* __restrict__ out){
    int tid = blockIdx.x*256 + threadIdx.x;
    if (tid >= NROWS*FOUTF/4) return;
    int b  = tid / (MM*FOUTF/4);
    int f4 = tid & 31;
    float4 yv = ((const float4*)Y)[tid];
    float4 uv = *(const float4*)(u + b*FOUTF + f4*4);
    float4 o;
    o.x = yv.x*uv.x; o.y = yv.y*uv.y; o.z = yv.z*uv.z; o.w = yv.w*uv.w;
    ((float4*)out)[tid] = o;
}

extern "C" void kernel_launch(void* const* d_in, const int* in_sizes, int n_in,
                              void* d_out, int out_size, void* d_ws, size_t ws_size,
                              hipStream_t stream){
    (void)in_sizes; (void)n_in; (void)out_size; (void)ws_size;
    const float* x    = (const float*)d_in[0];
    const float* lv   = (const float*)d_in[1];
    const int*   lr   = (const int*)d_in[2];
    const int*   lc   = (const int*)d_in[3];
    const float* kern = (const float*)d_in[4];
    const float* Wd   = (const float*)d_in[5];
    const float* bd   = (const float*)d_in[6];
    const float* Wu   = (const float*)d_in[7];
    const float* bu   = (const float*)d_in[8];
    float* out = (float*)d_out;

    char* w = (char*)d_ws;
    size_t off = 0;
    auto take = [&](size_t bytes)->char*{
        char* p = w + off; off += (bytes + 255) & ~(size_t)255; return p;
    };
    unsigned short* X[4];
    for (int i = 0; i < 4; ++i) X[i] = (unsigned short*)take((size_t)MM*XC*2);
    float* Y           = (float*)take((size_t)NROWS*FOUTF*4);
    unsigned short* Wt = (unsigned short*)take((size_t)FOUTF*CD*2);
    int* counts        = (int*)take((size_t)MM*4);
    int* offs          = (int*)take((size_t)(MM+1)*4);
    int* cursor        = (int*)take((size_t)MM*4);
    int2* edges        = (int2*)take((size_t)EE*8);
    int* part          = (int*)take((size_t)NSB*4);
    float* sacc        = (float*)take((size_t)BB*FOUTF*4);
    float* u           = (float*)take((size_t)BB*FOUTF*4);

    hipMemsetAsync(counts, 0, MM*4, stream);
    hipMemsetAsync(sacc, 0, BB*FOUTF*4, stream);

    k_init_x0<<<25000, 256, 0, stream>>>(x, X[0]);
    k_prepw<<<256, 256, 0, stream>>>(kern, Wt);
    k_hist<<<(EE+255)/256, 256, 0, stream>>>(lr, counts);
    k_scanA<<<NSB, 256, 0, stream>>>(counts, part);
    k_scanB<<<1, 128, 0, stream>>>(part);
    k_scanC<<<NSB, 256, 0, stream>>>(counts, part, offs, cursor);
    k_scatter<<<(EE+255)/256, 256, 0, stream>>>(lr, lc, lv, cursor, edges);

    // Chebyshev recurrence, column-slab-phased for cache residency
    for (int s = 0; s < SLABS; ++s){
        int cbase = s*SC;
        k_spmm_slab<<<MM/4, 256, 0, stream>>>(X[0], X[0], X[1], offs, edges, 1.0f, 0, cbase);
        k_spmm_slab<<<MM/4, 256, 0, stream>>>(X[1], X[0], X[2], offs, edges, 2.0f, 1, cbase);
        k_spmm_slab<<<MM/4, 256, 0, stream>>>(X[2], X[1], X[3], offs, edges, 2.0f, 1, cbase);
    }

    k_gemm<<<(NROWS+255)/256, 256, 0, stream>>>(X[0], X[1], X[2], X[3], Wt, Y, sacc);

    k_se<<<BB, 128, 0, stream>>>(sacc, Wd, bd, Wu, bu, u);
    k_scale<<<25000, 256, 0, stream>>>(Y, u, out);
}

// Round 3
// 833.044 us; speedup vs baseline: 1.0959x; 1.0295x over previous
//
#include <hip/hip_runtime.h>
#include <hip/hip_bf16.h>

#define BB 4
#define MM 50000
#define FINF 128
#define FOUTF 128
#define KCH 4
#define EE 800000
#define NROWS (BB*MM)      // 200000
#define XC 512             // columns of X = B*FIN
#define CD 512             // reduction dim = FIN*K
#define SLABS 4
#define SC (XC/SLABS)      // 128 shorts = 256 B per row-slab
#define SCB 512            // counts per scan block
#define NSB ((MM + SCB - 1)/SCB)   // 98
#define GXB ((MM + 255)/256)       // 196 row-blocks per batch in gemm

__device__ __forceinline__ float bf2f(unsigned short u){
    union{unsigned int i; float f;} v; v.i = ((unsigned int)u) << 16; return v.f;
}
__device__ __forceinline__ unsigned short f2bf(float f){
    union{float f; unsigned int i;} v; v.f = f;
    unsigned int r = v.i + 0x7FFF + ((v.i >> 16) & 1);   // RNE
    return (unsigned short)(r >> 16);
}

typedef __bf16 bf16x8 __attribute__((ext_vector_type(8)));
typedef float  f32x4  __attribute__((ext_vector_type(4)));

// ---- X0[m][b*128+f] = bf16(x[b][m][f]) ----
__global__ __launch_bounds__(256) void k_init_x0(const float* __restrict__ x,
                                                 unsigned short* __restrict__ X0){
    int tid = blockIdx.x*256 + threadIdx.x;          // one float4 each
    if (tid >= BB*MM*FINF/4) return;
    int f4 = tid & 31;
    int t  = tid >> 5;                               // b*MM + m
    int m  = t % MM, b = t / MM;
    float4 v = ((const float4*)x)[tid];
    ushort4 o;
    o.x = f2bf(v.x); o.y = f2bf(v.y); o.z = f2bf(v.z); o.w = f2bf(v.w);
    *(ushort4*)(X0 + (size_t)m*XC + b*FINF + f4*4) = o;
}

// ---- Wt swizzled into MFMA B-fragment order ----
__global__ __launch_bounds__(256) void k_prepw(const float* __restrict__ kern,
                                               unsigned short* __restrict__ Wt){
    int tid = blockIdx.x*256 + threadIdx.x;          // 65536
    int c = tid & 511, n = tid >> 9;
    int kc = c >> 7, f = c & 127;
    int ns = n >> 4, l16 = n & 15;
    int ks = c >> 5, rem = c & 31, g = rem >> 3, j = rem & 7;
    int lane = g*16 + l16;
    Wt[((ns*16 + ks)*64 + lane)*8 + j] = f2bf(kern[(f*KCH + kc)*FOUTF + n]);
}

// ---- CSR build ----
__global__ __launch_bounds__(256) void k_hist(const int* __restrict__ rows, int* __restrict__ counts){
    int e = blockIdx.x*256 + threadIdx.x;
    if (e < EE) atomicAdd(&counts[rows[e]], 1);
}

// parallel scan, 3 stages
__global__ __launch_bounds__(256) void k_scanA(const int* __restrict__ counts, int* __restrict__ part){
    __shared__ int red[256];
    int b = blockIdx.x, t = threadIdx.x;
    int i = b*SCB + t;
    int s = 0;
    if (i < MM) s += counts[i];
    if (i + 256 < (b+1)*SCB && i + 256 < MM) s += counts[i+256];
    red[t] = s; __syncthreads();
    for (int d = 128; d > 0; d >>= 1){
        if (t < d) red[t] += red[t+d];
        __syncthreads();
    }
    if (t == 0) part[b] = red[0];
}

__global__ __launch_bounds__(128) void k_scanB(int* __restrict__ part){
    __shared__ int sh[128];
    int t = threadIdx.x;
    sh[t] = (t < NSB) ? part[t] : 0;
    __syncthreads();
    for (int d = 1; d < 128; d <<= 1){
        int v = (t >= d) ? sh[t-d] : 0;
        __syncthreads();
        sh[t] += v;
        __syncthreads();
    }
    if (t < NSB) part[t] = sh[t];                    // inclusive sums
}

__global__ __launch_bounds__(256) void k_scanC(const int* __restrict__ counts, const int* __restrict__ part,
                                               int* __restrict__ offs, int* __restrict__ cursor){
    __shared__ int sh[256];
    int b = blockIdx.x, t = threadIdx.x;
    int base = (b == 0) ? 0 : part[b-1];
    int i0 = b*SCB + 2*t;
    int c0 = (i0     < MM) ? counts[i0]   : 0;
    int c1 = (i0 + 1 < MM) ? counts[i0+1] : 0;
    sh[t] = c0 + c1; __syncthreads();
    for (int d = 1; d < 256; d <<= 1){
        int v = (t >= d) ? sh[t-d] : 0;
        __syncthreads();
        sh[t] += v;
        __syncthreads();
    }
    int excl = base + sh[t] - (c0 + c1);
    if (i0 < MM){ offs[i0] = excl;      cursor[i0] = excl; }
    if (i0 + 1 < MM){ offs[i0+1] = excl + c0; cursor[i0+1] = excl + c0; }
    if (b == gridDim.x-1 && t == 255) offs[MM] = EE;
}

__global__ __launch_bounds__(256) void k_scatter(const int* __restrict__ rows, const int* __restrict__ cols,
                                                 const float* __restrict__ vals, int* __restrict__ cursor,
                                                 int2* __restrict__ edges){
    int e = blockIdx.x*256 + threadIdx.x;
    if (e >= EE) return;
    int r = rows[e];
    int pos = atomicAdd(&cursor[r], 1);
    edges[pos] = make_int2(cols[e], __float_as_int(vals[e]));
}

// ---- Xout_slab = alpha * (L @ Xin_slab) - (sub ? Xprev_slab : 0) ----
// Column-slab version: per dispatch the gather working set is MM*SC*2 = 12.8 MB.
__global__ __launch_bounds__(256) void k_spmm_slab(const unsigned short* __restrict__ Xin,
                                                   const unsigned short* __restrict__ Xprev,
                                                   unsigned short* __restrict__ Xout,
                                                   const int* __restrict__ offs,
                                                   const int2* __restrict__ edges,
                                                   float alpha, int sub, int cbase){
    int m    = blockIdx.x*4 + (threadIdx.x >> 6);    // grid 12500 * 4 rows = 50000 exact
    int lane = threadIdx.x & 63;
    size_t c0 = (size_t)cbase + lane*2;
    int start = offs[m], end = offs[m+1];
    float a0 = 0.f, a1 = 0.f;

    int nb = (end - start) & ~3;
    int burst_end = start + nb;
    int j = start;

    int2 ee[4];
    if (j < burst_end){
        #pragma unroll
        for (int q = 0; q < 4; ++q) ee[q] = edges[j+q];
    }
    while (j < burst_end){
        int2 e_[4];
        #pragma unroll
        for (int q = 0; q < 4; ++q) e_[q] = ee[q];
        j += 4;
        if (j < burst_end){
            #pragma unroll
            for (int q = 0; q < 4; ++q) ee[q] = edges[j+q];
        }
        ushort2 xv[4];
        #pragma unroll
        for (int q = 0; q < 4; ++q)
            xv[q] = *(const ushort2*)(Xin + (size_t)e_[q].x*XC + c0);
        #pragma unroll
        for (int q = 0; q < 4; ++q){
            float val = __int_as_float(e_[q].y);
            a0 += val*bf2f(xv[q].x); a1 += val*bf2f(xv[q].y);
        }
    }
    for (; j < end; ++j){
        int2 e = edges[j];
        float val = __int_as_float(e.y);
        ushort2 xv = *(const ushort2*)(Xin + (size_t)e.x*XC + c0);
        a0 += val*bf2f(xv.x); a1 += val*bf2f(xv.y);
    }

    a0 *= alpha; a1 *= alpha;
    if (sub){
        ushort2 pv = *(const ushort2*)(Xprev + (size_t)m*XC + c0);
        a0 -= bf2f(pv.x); a1 -= bf2f(pv.y);
    }
    ushort2 o; o.x = f2bf(a0); o.y = f2bf(a1);
    *(ushort2*)(Xout + (size_t)m*XC + c0) = o;
}

// ---- GEMM: grid (196 row-blocks, 4 batches). No block straddles a batch, so
// the column-sum epilogue is uniform: shuffle + LDS reduce + per-block partial
// store (contention-free, deterministic). Partials reduced in k_se. ----
__global__ __launch_bounds__(256, 2) void k_gemm(const unsigned short* __restrict__ X0,
                                                 const unsigned short* __restrict__ X1,
                                                 const unsigned short* __restrict__ X2,
                                                 const unsigned short* __restrict__ X3,
                                                 const unsigned short* __restrict__ Wt,
                                                 float* __restrict__ Y,
                                                 float* __restrict__ Ypart){
    const int wave = threadIdx.x >> 6;
    const int lane = threadIdx.x & 63;
    const int l16  = lane & 15;
    const int g    = lane >> 4;                       // 0..3
    const int bidx = blockIdx.y;                      // batch
    const int m0   = blockIdx.x*256 + wave*64;        // row within batch

    int aoff[4];                                      // short-index offsets into X
    #pragma unroll
    for (int i = 0; i < 4; ++i){
        int mr = m0 + i*16 + l16;
        if (mr >= MM) mr = MM-1;
        aoff[i] = mr*XC + bidx*FINF + g*8;
    }

    const unsigned short* const Xs[4] = {X0, X1, X2, X3};

    f32x4 acc[4][8];
    #pragma unroll
    for (int i = 0; i < 4; ++i)
        #pragma unroll
        for (int j = 0; j < 8; ++j) acc[i][j] = (f32x4){0.f,0.f,0.f,0.f};

    bf16x8 a_cur[4], b_cur[8], a_nxt[4], b_nxt[8];

    {   // preload ks = 0
        const unsigned short* Xb = Xs[0];
        #pragma unroll
        for (int i = 0; i < 4; ++i) a_cur[i] = *(const bf16x8*)(Xb + aoff[i]);
        #pragma unroll
        for (int ns = 0; ns < 8; ++ns) b_cur[ns] = *(const bf16x8*)(Wt + (ns*16)*512 + lane*8);
    }

    #pragma unroll
    for (int ks = 0; ks < 16; ++ks){
        if (ks < 15){
            const int kn = ks + 1;
            const unsigned short* Xb = Xs[kn >> 2];
            const int f0 = (kn & 3)*32;
            #pragma unroll
            for (int i = 0; i < 4; ++i) a_nxt[i] = *(const bf16x8*)(Xb + aoff[i] + f0);
            #pragma unroll
            for (int ns = 0; ns < 8; ++ns) b_nxt[ns] = *(const bf16x8*)(Wt + (ns*16 + kn)*512 + lane*8);
        }
        #pragma unroll
        for (int ns = 0; ns < 8; ++ns)
            #pragma unroll
            for (int i = 0; i < 4; ++i)
                acc[i][ns] = __builtin_amdgcn_mfma_f32_16x16x32_bf16(a_cur[i], b_cur[ns], acc[i][ns], 0, 0, 0);
        #pragma unroll
        for (int i = 0; i < 4; ++i) a_cur[i] = a_nxt[i];
        #pragma unroll
        for (int ns = 0; ns < 8; ++ns) b_cur[ns] = b_nxt[ns];
    }

    // epilogue: relu + store + per-block column partial sums
    __shared__ float ldsum[4][FOUTF];
    float csum[8];
    #pragma unroll
    for (int ns = 0; ns < 8; ++ns) csum[ns] = 0.f;

    #pragma unroll
    for (int i = 0; i < 4; ++i){
        #pragma unroll
        for (int reg = 0; reg < 4; ++reg){
            int mr = m0 + i*16 + g*4 + reg;
            if (mr < MM){
                #pragma unroll
                for (int ns = 0; ns < 8; ++ns){
                    float v = acc[i][ns][reg];
                    v = v > 0.f ? v : 0.f;
                    Y[((size_t)bidx*MM + mr)*FOUTF + ns*16 + l16] = v;
                    csum[ns] += v;
                }
            }
        }
    }
    #pragma unroll
    for (int ns = 0; ns < 8; ++ns){
        float v = csum[ns];
        v += __shfl_xor(v, 16);                       // sum over g = 0..3
        v += __shfl_xor(v, 32);
        csum[ns] = v;
    }
    if (lane < 16){
        #pragma unroll
        for (int ns = 0; ns < 8; ++ns) ldsum[wave][ns*16 + lane] = csum[ns];
    }
    __syncthreads();
    int t = threadIdx.x;
    if (t < FOUTF){
        float s = ldsum[0][t] + ldsum[1][t] + ldsum[2][t] + ldsum[3][t];
        Ypart[((size_t)bidx*GXB + blockIdx.x)*FOUTF + t] = s;
    }
}

// ---- SE MLP: reduce gemm partials -> mean -> u = sigmoid(swish(mean@Wd+bd)@Wu+bu) ----
__global__ __launch_bounds__(128) void k_se(const float* __restrict__ Ypart,
                                            const float* __restrict__ Wd, const float* __restrict__ bd,
                                            const float* __restrict__ Wu, const float* __restrict__ bu,
                                            float* __restrict__ u){
    int b = blockIdx.x, t = threadIdx.x;
    __shared__ float sm[128];
    __shared__ float dsh[16];
    float s = 0.f;
    for (int j = 0; j < GXB; ++j) s += Ypart[((size_t)b*GXB + j)*FOUTF + t];
    sm[t] = s * (1.0f/MM);
    __syncthreads();
    if (t < 16){
        float a = bd[t];
        for (int f = 0; f < 128; ++f) a += sm[f]*Wd[f*16 + t];
        dsh[t] = a / (1.f + expf(-a));                // swish
    }
    __syncthreads();
    float a = bu[t];
    for (int j = 0; j < 16; ++j) a += dsh[j]*Wu[j*FOUTF + t];
    u[b*FOUTF + t] = 1.f/(1.f + expf(-a));
}

// ---- out = Y * u[b] ----
__global__ __launch_bounds__(256) void k_scale(const float* __restrict__ Y, const float* __restrict__ u,
                                               float* __restrict__ out){
    int tid = blockIdx.x*256 + threadIdx.x;
    if (tid >= NROWS*FOUTF/4) return;
    int b  = tid / (MM*FOUTF/4);
    int f4 = tid & 31;
    float4 yv = ((const float4*)Y)[tid];
    float4 uv = *(const float4*)(u + b*FOUTF + f4*4);
    float4 o;
    o.x = yv.x*uv.x; o.y = yv.y*uv.y; o.z = yv.z*uv.z; o.w = yv.w*uv.w;
    ((float4*)out)[tid] = o;
}

extern "C" void kernel_launch(void* const* d_in, const int* in_sizes, int n_in,
                              void* d_out, int out_size, void* d_ws, size_t ws_size,
                              hipStream_t stream){
    (void)in_sizes; (void)n_in; (void)out_size; (void)ws_size;
    const float* x    = (const float*)d_in[0];
    const float* lv   = (const float*)d_in[1];
    const int*   lr   = (const int*)d_in[2];
    const int*   lc   = (const int*)d_in[3];
    const float* kern = (const float*)d_in[4];
    const float* Wd   = (const float*)d_in[5];
    const float* bd   = (const float*)d_in[6];
    const float* Wu   = (const float*)d_in[7];
    const float* bu   = (const float*)d_in[8];
    float* out = (float*)d_out;

    char* w = (char*)d_ws;
    size_t off = 0;
    auto take = [&](size_t bytes)->char*{
        char* p = w + off; off += (bytes + 255) & ~(size_t)255; return p;
    };
    unsigned short* X[4];
    for (int i = 0; i < 4; ++i) X[i] = (unsigned short*)take((size_t)MM*XC*2);
    float* Y           = (float*)take((size_t)NROWS*FOUTF*4);
    unsigned short* Wt = (unsigned short*)take((size_t)FOUTF*CD*2);
    int* counts        = (int*)take((size_t)MM*4);
    int* offs          = (int*)take((size_t)(MM+1)*4);
    int* cursor        = (int*)take((size_t)MM*4);
    int2* edges        = (int2*)take((size_t)EE*8);
    int* part          = (int*)take((size_t)NSB*4);
    float* Ypart       = (float*)take((size_t)BB*GXB*FOUTF*4);
    float* u           = (float*)take((size_t)BB*FOUTF*4);

    hipMemsetAsync(counts, 0, MM*4, stream);

    k_init_x0<<<25000, 256, 0, stream>>>(x, X[0]);
    k_prepw<<<256, 256, 0, stream>>>(kern, Wt);
    k_hist<<<(EE+255)/256, 256, 0, stream>>>(lr, counts);
    k_scanA<<<NSB, 256, 0, stream>>>(counts, part);
    k_scanB<<<1, 128, 0, stream>>>(part);
    k_scanC<<<NSB, 256, 0, stream>>>(counts, part, offs, cursor);
    k_scatter<<<(EE+255)/256, 256, 0, stream>>>(lr, lc, lv, cursor, edges);

    // Chebyshev recurrence, column-slab-phased for cache residency
    for (int s = 0; s < SLABS; ++s){
        int cbase = s*SC;
        k_spmm_slab<<<MM/4, 256, 0, stream>>>(X[0], X[0], X[1], offs, edges, 1.0f, 0, cbase);
        k_spmm_slab<<<MM/4, 256, 0, stream>>>(X[1], X[0], X[2], offs, edges, 2.0f, 1, cbase);
        k_spmm_slab<<<MM/4, 256, 0, stream>>>(X[2], X[1], X[3], offs, edges, 2.0f, 1, cbase);
    }

    dim3 ggemm(GXB, BB);
    k_gemm<<<ggemm, 256, 0, stream>>>(X[0], X[1], X[2], X[3], Wt, Y, Ypart);

    k_se<<<BB, 128, 0, stream>>>(Ypart, Wd, bd, Wu, bu, u);
    k_scale<<<25000, 256, 0, stream>>>(Y, u, out);
}

// Round 4
// 790.899 us; speedup vs baseline: 1.1543x; 1.0533x over previous
//
#include <hip/hip_runtime.h>
#include <hip/hip_bf16.h>

#define BB 4
#define MM 50000
#define FINF 128
#define FOUTF 128
#define KCH 4
#define EE 800000
#define NROWS (BB*MM)      // 200000
#define XC 512             // columns of X = B*FIN
#define CD 512             // reduction dim = FIN*K
#define SLABS 4
#define SC (XC/SLABS)      // 128 shorts = 256 B per row-slab
#define SCB 512            // counts per scan block
#define NSB ((MM + SCB - 1)/SCB)   // 98
#define GXB ((MM + 255)/256)       // 196 row-blocks per batch in gemm

__device__ __forceinline__ float bf2f(unsigned short u){
    union{unsigned int i; float f;} v; v.i = ((unsigned int)u) << 16; return v.f;
}
__device__ __forceinline__ unsigned short f2bf(float f){
    union{float f; unsigned int i;} v; v.f = f;
    unsigned int r = v.i + 0x7FFF + ((v.i >> 16) & 1);   // RNE
    return (unsigned short)(r >> 16);
}

typedef __bf16 bf16x8 __attribute__((ext_vector_type(8)));
typedef float  f32x4  __attribute__((ext_vector_type(4)));

typedef __attribute__((address_space(3))) unsigned int       lds_uint;
typedef const __attribute__((address_space(1))) unsigned int gbl_uint;

// ---- X0[m][b*128+f] = bf16(x[b][m][f]) ----
__global__ __launch_bounds__(256) void k_init_x0(const float* __restrict__ x,
                                                 unsigned short* __restrict__ X0){
    int tid = blockIdx.x*256 + threadIdx.x;          // one float4 each
    if (tid >= BB*MM*FINF/4) return;
    int f4 = tid & 31;
    int t  = tid >> 5;                               // b*MM + m
    int m  = t % MM, b = t / MM;
    float4 v = ((const float4*)x)[tid];
    ushort4 o;
    o.x = f2bf(v.x); o.y = f2bf(v.y); o.z = f2bf(v.z); o.w = f2bf(v.w);
    *(ushort4*)(X0 + (size_t)m*XC + b*FINF + f4*4) = o;
}

// ---- Wt swizzled into MFMA B-fragment order ----
__global__ __launch_bounds__(256) void k_prepw(const float* __restrict__ kern,
                                               unsigned short* __restrict__ Wt){
    int tid = blockIdx.x*256 + threadIdx.x;          // 65536
    int c = tid & 511, n = tid >> 9;
    int kc = c >> 7, f = c & 127;
    int ns = n >> 4, l16 = n & 15;
    int ks = c >> 5, rem = c & 31, g = rem >> 3, j = rem & 7;
    int lane = g*16 + l16;
    Wt[((ns*16 + ks)*64 + lane)*8 + j] = f2bf(kern[(f*KCH + kc)*FOUTF + n]);
}

// ---- CSR build ----
__global__ __launch_bounds__(256) void k_hist(const int* __restrict__ rows, int* __restrict__ counts){
    int e = blockIdx.x*256 + threadIdx.x;
    if (e < EE) atomicAdd(&counts[rows[e]], 1);
}

// parallel scan, 3 stages
__global__ __launch_bounds__(256) void k_scanA(const int* __restrict__ counts, int* __restrict__ part){
    __shared__ int red[256];
    int b = blockIdx.x, t = threadIdx.x;
    int i = b*SCB + t;
    int s = 0;
    if (i < MM) s += counts[i];
    if (i + 256 < (b+1)*SCB && i + 256 < MM) s += counts[i+256];
    red[t] = s; __syncthreads();
    for (int d = 128; d > 0; d >>= 1){
        if (t < d) red[t] += red[t+d];
        __syncthreads();
    }
    if (t == 0) part[b] = red[0];
}

__global__ __launch_bounds__(128) void k_scanB(int* __restrict__ part){
    __shared__ int sh[128];
    int t = threadIdx.x;
    sh[t] = (t < NSB) ? part[t] : 0;
    __syncthreads();
    for (int d = 1; d < 128; d <<= 1){
        int v = (t >= d) ? sh[t-d] : 0;
        __syncthreads();
        sh[t] += v;
        __syncthreads();
    }
    if (t < NSB) part[t] = sh[t];                    // inclusive sums
}

__global__ __launch_bounds__(256) void k_scanC(const int* __restrict__ counts, const int* __restrict__ part,
                                               int* __restrict__ offs, int* __restrict__ cursor){
    __shared__ int sh[256];
    int b = blockIdx.x, t = threadIdx.x;
    int base = (b == 0) ? 0 : part[b-1];
    int i0 = b*SCB + 2*t;
    int c0 = (i0     < MM) ? counts[i0]   : 0;
    int c1 = (i0 + 1 < MM) ? counts[i0+1] : 0;
    sh[t] = c0 + c1; __syncthreads();
    for (int d = 1; d < 256; d <<= 1){
        int v = (t >= d) ? sh[t-d] : 0;
        __syncthreads();
        sh[t] += v;
        __syncthreads();
    }
    int excl = base + sh[t] - (c0 + c1);
    if (i0 < MM){ offs[i0] = excl;      cursor[i0] = excl; }
    if (i0 + 1 < MM){ offs[i0+1] = excl + c0; cursor[i0+1] = excl + c0; }
    if (b == gridDim.x-1 && t == 255) offs[MM] = EE;
}

__global__ __launch_bounds__(256) void k_scatter(const int* __restrict__ rows, const int* __restrict__ cols,
                                                 const float* __restrict__ vals, int* __restrict__ cursor,
                                                 int2* __restrict__ edges){
    int e = blockIdx.x*256 + threadIdx.x;
    if (e >= EE) return;
    int r = rows[e];
    int pos = atomicAdd(&cursor[r], 1);
    edges[pos] = make_int2(cols[e], __float_as_int(vals[e]));
}

// ---- Xout_slab = alpha * (L @ Xin_slab) - (sub ? Xprev_slab : 0) ----
// Column-slab version: per dispatch the gather working set is MM*SC*2 = 12.8 MB.
__global__ __launch_bounds__(256) void k_spmm_slab(const unsigned short* __restrict__ Xin,
                                                   const unsigned short* __restrict__ Xprev,
                                                   unsigned short* __restrict__ Xout,
                                                   const int* __restrict__ offs,
                                                   const int2* __restrict__ edges,
                                                   float alpha, int sub, int cbase){
    int m    = blockIdx.x*4 + (threadIdx.x >> 6);    // grid 12500 * 4 rows = 50000 exact
    int lane = threadIdx.x & 63;
    size_t c0 = (size_t)cbase + lane*2;
    int start = offs[m], end = offs[m+1];
    float a0 = 0.f, a1 = 0.f;

    int nb = (end - start) & ~3;
    int burst_end = start + nb;
    int j = start;

    int2 ee[4];
    if (j < burst_end){
        #pragma unroll
        for (int q = 0; q < 4; ++q) ee[q] = edges[j+q];
    }
    while (j < burst_end){
        int2 e_[4];
        #pragma unroll
        for (int q = 0; q < 4; ++q) e_[q] = ee[q];
        j += 4;
        if (j < burst_end){
            #pragma unroll
            for (int q = 0; q < 4; ++q) ee[q] = edges[j+q];
        }
        ushort2 xv[4];
        #pragma unroll
        for (int q = 0; q < 4; ++q)
            xv[q] = *(const ushort2*)(Xin + (size_t)e_[q].x*XC + c0);
        #pragma unroll
        for (int q = 0; q < 4; ++q){
            float val = __int_as_float(e_[q].y);
            a0 += val*bf2f(xv[q].x); a1 += val*bf2f(xv[q].y);
        }
    }
    for (; j < end; ++j){
        int2 e = edges[j];
        float val = __int_as_float(e.y);
        ushort2 xv = *(const ushort2*)(Xin + (size_t)e.x*XC + c0);
        a0 += val*bf2f(xv.x); a1 += val*bf2f(xv.y);
    }

    a0 *= alpha; a1 *= alpha;
    if (sub){
        ushort2 pv = *(const ushort2*)(Xprev + (size_t)m*XC + c0);
        a0 -= bf2f(pv.x); a1 -= bf2f(pv.y);
    }
    ushort2 o; o.x = f2bf(a0); o.y = f2bf(a1);
    *(ushort2*)(Xout + (size_t)m*XC + c0) = o;
}

// ---- GEMM: 256 rows x 128 cols per block, A+B staged via global_load_lds
// double-buffered LDS (BK=32, 16 k-steps). A-tile LDS uses XOR swizzle
// byte ^= ((row&6)<<3) applied on BOTH staging source and ds_read (G21) to
// break the 8-way bank conflict of 64-B-row fragments. B staged once per
// block per k-step (kills the 4x redundant per-wave Wt loads). ----
__global__ __launch_bounds__(256, 2) void k_gemm(const unsigned short* __restrict__ X0,
                                                 const unsigned short* __restrict__ X1,
                                                 const unsigned short* __restrict__ X2,
                                                 const unsigned short* __restrict__ X3,
                                                 const unsigned short* __restrict__ Wt,
                                                 float* __restrict__ Y,
                                                 float* __restrict__ Ypart){
    const int wave = threadIdx.x >> 6;
    const int lane = threadIdx.x & 63;
    const int l16  = lane & 15;
    const int g    = lane >> 4;                       // 0..3
    const int bidx = blockIdx.y;                      // batch
    const int m0   = blockIdx.x*256;                  // row-tile base (rows m0..m0+255)

    __shared__ unsigned short As[2][8192];            // 2 x 16 KB: 256 rows x 32 k (swizzled)
    __shared__ unsigned short Bs[2][4096];            // 2 x 8 KB: 128 cols x 32 k (frag order)

    const unsigned short* const Xs[4] = {X0, X1, X2, X3};

    f32x4 acc[4][8];
    #pragma unroll
    for (int i = 0; i < 4; ++i)
        #pragma unroll
        for (int j = 0; j < 8; ++j) acc[i][j] = (f32x4){0.f,0.f,0.f,0.f};

    // stage k-step ks into buffer buf (all 4 waves participate; 6 DMA issues/wave)
    auto stage = [&](int buf, int ks){
        const unsigned short* Xb = Xs[ks >> 2];
        const int f0 = (ks & 3)*64;                   // byte offset of 32-k slice in 256-B batch row
        #pragma unroll
        for (int q = 0; q < 4; ++q){                  // A: 16 KB = 4 waves x 4 x 1 KB
            int row = q*64 + wave*16 + (lane >> 2);
            int mr  = m0 + row; if (mr >= MM) mr = MM-1;
            int inner = ((lane & 3)*16) ^ ((row & 6) << 3);   // source pre-swizzle
            const char* src = (const char*)Xb + (size_t)mr*1024 + bidx*256 + f0 + inner;
            lds_uint* dst = (lds_uint*)(&As[buf][(q*4096 + wave*1024)/2]);   // wave-uniform base
            __builtin_amdgcn_global_load_lds((gbl_uint*)src, dst, 16, 0, 0);
        }
        #pragma unroll
        for (int q = 0; q < 2; ++q){                  // B: 8 KB = 4 waves x 2 x 1 KB
            int ns = q*4 + wave;
            const char* src = (const char*)Wt + (size_t)(ns*16 + ks)*1024 + lane*16;
            lds_uint* dst = (lds_uint*)(&Bs[buf][ns*512]);                   // wave-uniform base
            __builtin_amdgcn_global_load_lds((gbl_uint*)src, dst, 16, 0, 0);
        }
    };

    stage(0, 0);
    __syncthreads();

    for (int ks = 0; ks < 16; ++ks){
        const int buf = ks & 1;
        if (ks < 15) stage(buf ^ 1, ks + 1);

        bf16x8 a[4];
        #pragma unroll
        for (int i = 0; i < 4; ++i){
            int rr = wave*64 + i*16 + l16;
            int phys = rr*64 + ((g*16) ^ ((rr & 6) << 3));    // matching read swizzle
            a[i] = *(const bf16x8*)((const char*)&As[buf][0] + phys);
        }
        #pragma unroll
        for (int ns = 0; ns < 8; ++ns){
            bf16x8 b = *(const bf16x8*)(&Bs[buf][ns*512 + lane*8]);
            #pragma unroll
            for (int i = 0; i < 4; ++i)
                acc[i][ns] = __builtin_amdgcn_mfma_f32_16x16x32_bf16(a[i], b, acc[i][ns], 0, 0, 0);
        }
        __syncthreads();
    }

    // epilogue: relu + store + per-block column partial sums
    __shared__ float ldsum[4][FOUTF];
    float csum[8];
    #pragma unroll
    for (int ns = 0; ns < 8; ++ns) csum[ns] = 0.f;

    #pragma unroll
    for (int i = 0; i < 4; ++i){
        #pragma unroll
        for (int reg = 0; reg < 4; ++reg){
            int mr = m0 + wave*64 + i*16 + g*4 + reg;
            if (mr < MM){
                #pragma unroll
                for (int ns = 0; ns < 8; ++ns){
                    float v = acc[i][ns][reg];
                    v = v > 0.f ? v : 0.f;
                    Y[((size_t)bidx*MM + mr)*FOUTF + ns*16 + l16] = v;
                    csum[ns] += v;
                }
            }
        }
    }
    #pragma unroll
    for (int ns = 0; ns < 8; ++ns){
        float v = csum[ns];
        v += __shfl_xor(v, 16);                       // sum over g = 0..3
        v += __shfl_xor(v, 32);
        csum[ns] = v;
    }
    if (lane < 16){
        #pragma unroll
        for (int ns = 0; ns < 8; ++ns) ldsum[wave][ns*16 + lane] = csum[ns];
    }
    __syncthreads();
    int t = threadIdx.x;
    if (t < FOUTF){
        float s = ldsum[0][t] + ldsum[1][t] + ldsum[2][t] + ldsum[3][t];
        Ypart[((size_t)bidx*GXB + blockIdx.x)*FOUTF + t] = s;
    }
}

// ---- SE MLP: reduce gemm partials -> mean -> u = sigmoid(swish(mean@Wd+bd)@Wu+bu) ----
__global__ __launch_bounds__(128) void k_se(const float* __restrict__ Ypart,
                                            const float* __restrict__ Wd, const float* __restrict__ bd,
                                            const float* __restrict__ Wu, const float* __restrict__ bu,
                                            float* __restrict__ u){
    int b = blockIdx.x, t = threadIdx.x;
    __shared__ float sm[128];
    __shared__ float dsh[16];
    float s = 0.f;
    for (int j = 0; j < GXB; ++j) s += Ypart[((size_t)b*GXB + j)*FOUTF + t];
    sm[t] = s * (1.0f/MM);
    __syncthreads();
    if (t < 16){
        float a = bd[t];
        for (int f = 0; f < 128; ++f) a += sm[f]*Wd[f*16 + t];
        dsh[t] = a / (1.f + expf(-a));                // swish
    }
    __syncthreads();
    float a = bu[t];
    for (int j = 0; j < 16; ++j) a += dsh[j]*Wu[j*FOUTF + t];
    u[b*FOUTF + t] = 1.f/(1.f + expf(-a));
}

// ---- out = Y * u[b] ----
__global__ __launch_bounds__(256) void k_scale(const float* __restrict__ Y, const float* __restrict__ u,
                                               float* __restrict__ out){
    int tid = blockIdx.x*256 + threadIdx.x;
    if (tid >= NROWS*FOUTF/4) return;
    int b  = tid / (MM*FOUTF/4);
    int f4 = tid & 31;
    float4 yv = ((const float4*)Y)[tid];
    float4 uv = *(const float4*)(u + b*FOUTF + f4*4);
    float4 o;
    o.x = yv.x*uv.x; o.y = yv.y*uv.y; o.z = yv.z*uv.z; o.w = yv.w*uv.w;
    ((float4*)out)[tid] = o;
}

extern "C" void kernel_launch(void* const* d_in, const int* in_sizes, int n_in,
                              void* d_out, int out_size, void* d_ws, size_t ws_size,
                              hipStream_t stream){
    (void)in_sizes; (void)n_in; (void)out_size; (void)ws_size;
    const float* x    = (const float*)d_in[0];
    const float* lv   = (const float*)d_in[1];
    const int*   lr   = (const int*)d_in[2];
    const int*   lc   = (const int*)d_in[3];
    const float* kern = (const float*)d_in[4];
    const float* Wd   = (const float*)d_in[5];
    const float* bd   = (const float*)d_in[6];
    const float* Wu   = (const float*)d_in[7];
    const float* bu   = (const float*)d_in[8];
    float* out = (float*)d_out;

    char* w = (char*)d_ws;
    size_t off = 0;
    auto take = [&](size_t bytes)->char*{
        char* p = w + off; off += (bytes + 255) & ~(size_t)255; return p;
    };
    unsigned short* X[4];
    for (int i = 0; i < 4; ++i) X[i] = (unsigned short*)take((size_t)MM*XC*2);
    float* Y           = (float*)take((size_t)NROWS*FOUTF*4);
    unsigned short* Wt = (unsigned short*)take((size_t)FOUTF*CD*2);
    int* counts        = (int*)take((size_t)MM*4);
    int* offs          = (int*)take((size_t)(MM+1)*4);
    int* cursor        = (int*)take((size_t)MM*4);
    int2* edges        = (int2*)take((size_t)EE*8);
    int* part          = (int*)take((size_t)NSB*4);
    float* Ypart       = (float*)take((size_t)BB*GXB*FOUTF*4);
    float* u           = (float*)take((size_t)BB*FOUTF*4);

    hipMemsetAsync(counts, 0, MM*4, stream);

    k_init_x0<<<25000, 256, 0, stream>>>(x, X[0]);
    k_prepw<<<256, 256, 0, stream>>>(kern, Wt);
    k_hist<<<(EE+255)/256, 256, 0, stream>>>(lr, counts);
    k_scanA<<<NSB, 256, 0, stream>>>(counts, part);
    k_scanB<<<1, 128, 0, stream>>>(part);
    k_scanC<<<NSB, 256, 0, stream>>>(counts, part, offs, cursor);
    k_scatter<<<(EE+255)/256, 256, 0, stream>>>(lr, lc, lv, cursor, edges);

    // Chebyshev recurrence, column-slab-phased for cache residency
    for (int s = 0; s < SLABS; ++s){
        int cbase = s*SC;
        k_spmm_slab<<<MM/4, 256, 0, stream>>>(X[0], X[0], X[1], offs, edges, 1.0f, 0, cbase);
        k_spmm_slab<<<MM/4, 256, 0, stream>>>(X[1], X[0], X[2], offs, edges, 2.0f, 1, cbase);
        k_spmm_slab<<<MM/4, 256, 0, stream>>>(X[2], X[1], X[3], offs, edges, 2.0f, 1, cbase);
    }

    dim3 ggemm(GXB, BB);
    k_gemm<<<ggemm, 256, 0, stream>>>(X[0], X[1], X[2], X[3], Wt, Y, Ypart);

    k_se<<<BB, 128, 0, stream>>>(Ypart, Wd, bd, Wu, bu, u);
    k_scale<<<25000, 256, 0, stream>>>(Y, u, out);
}